// Round 1
// baseline (824.416 us; speedup 1.0000x reference)
//
#include <hip/hip_runtime.h>

#define N_NODES 100000
#define N_EDGES 1600000

static constexpr int SCAN_CHUNK = 1024;
static constexpr int NB_SCAN = (N_NODES + SCAN_CHUNK - 1) / SCAN_CHUNK; // 98

// ---------------- degree / CSR build ----------------

__global__ __launch_bounds__(256) void count_deg_k(const int* __restrict__ dst,
                                                   int* __restrict__ counts) {
  int e = blockIdx.x * 256 + threadIdx.x;
  if (e < N_EDGES) atomicAdd(&counts[dst[e]], 1);
}

__global__ __launch_bounds__(256) void node_init_k(const int* __restrict__ counts,
                                                   float* __restrict__ dis,
                                                   float* __restrict__ selfn) {
  int i = blockIdx.x * 256 + threadIdx.x;
  if (i < N_NODES) {
    float deg = (float)counts[i] + 1.0f;  // +1 self loop
    dis[i] = rsqrtf(deg);
    selfn[i] = 1.0f / deg;
  }
}

__global__ __launch_bounds__(256) void scanA_k(const int* __restrict__ counts,
                                               int* __restrict__ blockSums) {
  __shared__ int sm[256];
  int b = blockIdx.x;
  int s = 0;
  for (int j = 0; j < 4; ++j) {
    int i = b * SCAN_CHUNK + j * 256 + threadIdx.x;
    if (i < N_NODES) s += counts[i];
  }
  sm[threadIdx.x] = s;
  __syncthreads();
  for (int off = 128; off > 0; off >>= 1) {
    if (threadIdx.x < off) sm[threadIdx.x] += sm[threadIdx.x + off];
    __syncthreads();
  }
  if (threadIdx.x == 0) blockSums[b] = sm[0];
}

__global__ void scanB_k(const int* __restrict__ blockSums,
                        int* __restrict__ blockOffs,
                        int* __restrict__ offsets) {
  __shared__ int sm[128];
  int t = threadIdx.x;  // blockDim = 128
  int v = (t < NB_SCAN) ? blockSums[t] : 0;
  sm[t] = v;
  __syncthreads();
  for (int off = 1; off < 128; off <<= 1) {
    int add = (t >= off) ? sm[t - off] : 0;
    __syncthreads();
    sm[t] += add;
    __syncthreads();
  }
  if (t < NB_SCAN) blockOffs[t] = sm[t] - v;  // exclusive
  if (t == 0) offsets[N_NODES] = N_EDGES;
}

__global__ __launch_bounds__(256) void scanC_k(const int* __restrict__ counts,
                                               const int* __restrict__ blockOffs,
                                               int* __restrict__ offsets,
                                               int* __restrict__ cursor) {
  __shared__ int sm[256];
  int b = blockIdx.x;
  int base = b * SCAN_CHUNK + threadIdx.x * 4;
  int v[4];
  int s = 0;
  for (int j = 0; j < 4; ++j) {
    int i = base + j;
    v[j] = (i < N_NODES) ? counts[i] : 0;
    s += v[j];
  }
  sm[threadIdx.x] = s;
  __syncthreads();
  for (int off = 1; off < 256; off <<= 1) {
    int add = (threadIdx.x >= off) ? sm[threadIdx.x - off] : 0;
    __syncthreads();
    sm[threadIdx.x] += add;
    __syncthreads();
  }
  int ex = blockOffs[b] + sm[threadIdx.x] - s;  // exclusive prefix for this thread
  for (int j = 0; j < 4; ++j) {
    int i = base + j;
    if (i < N_NODES) { offsets[i] = ex; cursor[i] = ex; }
    ex += v[j];
  }
}

__global__ __launch_bounds__(256) void fill_k(const int* __restrict__ src,
                                              const int* __restrict__ dst,
                                              int* __restrict__ cursor,
                                              int* __restrict__ csr_src) {
  int e = blockIdx.x * 256 + threadIdx.x;
  if (e < N_EDGES) {
    int d = dst[e];
    int p = atomicAdd(&cursor[d], 1);
    csr_src[p] = src[e];
  }
}

// ---------------- GEMM: out[N,C] = act(A)[N,K] @ W[K,C] + bias ----------------
// act = identity (BN=false) or relu(a*scale[k]+shift[k]) (BN=true), fused at staging.

template <int K, int C, int RPT, bool BN>
__global__ __launch_bounds__(256) void gemm_k(const float* __restrict__ A,
                                              const float* __restrict__ W,
                                              const float* __restrict__ bias,
                                              const float* __restrict__ scale,
                                              const float* __restrict__ shift,
                                              float* __restrict__ out) {
  constexpr int CQ = C / 4;        // float4 channel groups
  constexpr int TR = 256 / CQ;     // thread row-slots (floor)
  constexpr int ROWS = TR * RPT;   // rows per block
  __shared__ __align__(16) float Wl[K * C];
  __shared__ __align__(16) float Al[ROWS * K];
  const int tid = threadIdx.x;
  for (int i = tid; i < K * C; i += 256) Wl[i] = W[i];
  const int row0 = blockIdx.x * ROWS;
  for (int i = tid; i < ROWS * K; i += 256) {
    int r = i / K, k = i - r * K;
    int gr = row0 + r;
    float v = 0.f;
    if (gr < N_NODES) {
      v = A[(size_t)gr * K + k];
      if (BN) v = fmaxf(fmaf(v, scale[k], shift[k]), 0.f);
    }
    Al[i] = v;
  }
  __syncthreads();
  const int cq = tid % CQ;
  const int rs = tid / CQ;
  if (rs >= TR) return;  // only possible when 256 % CQ != 0 (C=40); no further barriers
  const float4* W4 = (const float4*)Wl;
  const float4* A4 = (const float4*)Al;
  float4 acc[RPT];
#pragma unroll
  for (int i = 0; i < RPT; ++i) acc[i] = make_float4(0.f, 0.f, 0.f, 0.f);
#pragma unroll 4
  for (int k4 = 0; k4 < K / 4; ++k4) {
    float4 w0 = W4[(4 * k4 + 0) * CQ + cq];
    float4 w1 = W4[(4 * k4 + 1) * CQ + cq];
    float4 w2 = W4[(4 * k4 + 2) * CQ + cq];
    float4 w3 = W4[(4 * k4 + 3) * CQ + cq];
#pragma unroll
    for (int i = 0; i < RPT; ++i) {
      float4 a = A4[(rs * RPT + i) * (K / 4) + k4];
      acc[i].x = fmaf(a.x, w0.x, acc[i].x); acc[i].y = fmaf(a.x, w0.y, acc[i].y);
      acc[i].z = fmaf(a.x, w0.z, acc[i].z); acc[i].w = fmaf(a.x, w0.w, acc[i].w);
      acc[i].x = fmaf(a.y, w1.x, acc[i].x); acc[i].y = fmaf(a.y, w1.y, acc[i].y);
      acc[i].z = fmaf(a.y, w1.z, acc[i].z); acc[i].w = fmaf(a.y, w1.w, acc[i].w);
      acc[i].x = fmaf(a.z, w2.x, acc[i].x); acc[i].y = fmaf(a.z, w2.y, acc[i].y);
      acc[i].z = fmaf(a.z, w2.z, acc[i].z); acc[i].w = fmaf(a.z, w2.w, acc[i].w);
      acc[i].x = fmaf(a.w, w3.x, acc[i].x); acc[i].y = fmaf(a.w, w3.y, acc[i].y);
      acc[i].z = fmaf(a.w, w3.z, acc[i].z); acc[i].w = fmaf(a.w, w3.w, acc[i].w);
    }
  }
  float4 b4 = ((const float4*)bias)[cq];
#pragma unroll
  for (int i = 0; i < RPT; ++i) {
    int gr = row0 + rs * RPT + i;
    if (gr < N_NODES) {
      float4 o = make_float4(acc[i].x + b4.x, acc[i].y + b4.y,
                             acc[i].z + b4.z, acc[i].w + b4.w);
      *((float4*)(out + (size_t)gr * C) + cq) = o;
    }
  }
}

// ---------------- aggregation: out[n] = dis[n]*sum_{e:dst=n} t[src_e]*dis[src_e] + t[n]*selfn[n]
// one wave per node, lane = channel; optional fused BN sum/sumsq stats.

template <int C, bool STATS>
__global__ __launch_bounds__(256) void agg_k(const float* __restrict__ t,
                                             const int* __restrict__ csr,
                                             const int* __restrict__ offs,
                                             const float* __restrict__ dis,
                                             const float* __restrict__ selfn,
                                             float* __restrict__ out,
                                             float* __restrict__ part) {
  __shared__ float s_sum[64];
  __shared__ float s_sq[64];
  if (STATS) {
    if (threadIdx.x < 64) { s_sum[threadIdx.x] = 0.f; s_sq[threadIdx.x] = 0.f; }
    __syncthreads();
  }
  const int lane = threadIdx.x & 63;
  const int node = blockIdx.x * 4 + (threadIdx.x >> 6);
  float v = 0.f;
  if (node < N_NODES) {
    const int beg = offs[node], end = offs[node + 1];
    float acc = 0.f;
    for (int base = beg; base < end; base += 64) {
      const int m = min(64, end - base);
      int sl = 0; float wl = 0.f;
      if (lane < m) { sl = csr[base + lane]; wl = dis[sl]; }
      for (int j = 0; j < m; ++j) {
        const int s = __shfl(sl, j);
        const float ww = __shfl(wl, j);
        if (lane < C) acc = fmaf(t[(size_t)s * C + lane], ww, acc);
      }
    }
    if (lane < C) {
      v = fmaf(dis[node], acc, t[(size_t)node * C + lane] * selfn[node]);
      out[(size_t)node * C + lane] = v;
    }
  }
  if (STATS) {
    atomicAdd(&s_sum[lane], v);
    atomicAdd(&s_sq[lane], v * v);
    __syncthreads();
    if (threadIdx.x < 128) {
      const int c = threadIdx.x & 63;
      const float val = (threadIdx.x < 64) ? s_sum[c] : s_sq[c];
      atomicAdd(&part[(blockIdx.x & 63) * 128 + (threadIdx.x < 64 ? c : 64 + c)], val);
    }
  }
}

__global__ void bnfinal_k(const float* __restrict__ part, const float* __restrict__ g,
                          const float* __restrict__ be, float* __restrict__ scale,
                          float* __restrict__ shift) {
  const int c = threadIdx.x;  // 64 threads
  float s = 0.f, q = 0.f;
  for (int b = 0; b < 64; ++b) { s += part[b * 128 + c]; q += part[b * 128 + 64 + c]; }
  const float inv = 1.0f / (float)N_NODES;
  const float mu = s * inv;
  const float var = q * inv - mu * mu;
  const float sc = g[c] * rsqrtf(var + 1e-5f);
  scale[c] = sc;
  shift[c] = fmaf(-mu, sc, be[c]);
}

// ---------------- launch ----------------

extern "C" void kernel_launch(void* const* d_in, const int* in_sizes, int n_in,
                              void* d_out, int out_size, void* d_ws, size_t ws_size,
                              hipStream_t stream) {
  const float* x   = (const float*)d_in[0];
  const int*   ei  = (const int*)d_in[1];
  const float* W1  = (const float*)d_in[2];
  const float* b1  = (const float*)d_in[3];
  const float* g1  = (const float*)d_in[4];
  const float* be1 = (const float*)d_in[5];
  const float* W2  = (const float*)d_in[6];
  const float* b2  = (const float*)d_in[7];
  const float* g2  = (const float*)d_in[8];
  const float* be2 = (const float*)d_in[9];
  const float* W3  = (const float*)d_in[10];
  const float* b3  = (const float*)d_in[11];
  float* out = (float*)d_out;
  const int* src = ei;
  const int* dst = ei + N_EDGES;

  char* ws = (char*)d_ws;
  size_t o = 0;
  auto alloc = [&](size_t bytes) -> char* {
    char* p = ws + o;
    o += (bytes + 255) & ~(size_t)255;
    return p;
  };
  int*   counts    = (int*)alloc((size_t)N_NODES * 4);
  int*   offsets   = (int*)alloc(((size_t)N_NODES + 1) * 4);
  int*   cursor    = (int*)alloc((size_t)N_NODES * 4);
  int*   csr_src   = (int*)alloc((size_t)N_EDGES * 4);
  float* dis       = (float*)alloc((size_t)N_NODES * 4);
  float* selfn     = (float*)alloc((size_t)N_NODES * 4);
  int*   blockSums = (int*)alloc(NB_SCAN * 4);
  int*   blockOffs = (int*)alloc(NB_SCAN * 4);
  float* part1     = (float*)alloc(64 * 128 * 4);  // 32 KiB, 256-aligned
  float* part2     = (float*)alloc(64 * 128 * 4);  // contiguous with part1
  float* scale1    = (float*)alloc(64 * 4);
  float* shift1    = (float*)alloc(64 * 4);
  float* scale2    = (float*)alloc(64 * 4);
  float* shift2    = (float*)alloc(64 * 4);
  float* tbuf      = (float*)alloc((size_t)N_NODES * 64 * 4);
  float* hbuf      = (float*)alloc((size_t)N_NODES * 64 * 4);

  hipMemsetAsync(counts, 0, (size_t)N_NODES * 4, stream);
  hipMemsetAsync(part1, 0, 2 * 64 * 128 * 4, stream);  // part1+part2

  count_deg_k<<<(N_EDGES + 255) / 256, 256, 0, stream>>>(dst, counts);
  node_init_k<<<(N_NODES + 255) / 256, 256, 0, stream>>>(counts, dis, selfn);
  scanA_k<<<NB_SCAN, 256, 0, stream>>>(counts, blockSums);
  scanB_k<<<1, 128, 0, stream>>>(blockSums, blockOffs, offsets);
  scanC_k<<<NB_SCAN, 256, 0, stream>>>(counts, blockOffs, offsets, cursor);
  fill_k<<<(N_EDGES + 255) / 256, 256, 0, stream>>>(src, dst, cursor, csr_src);

  // layer 1: K=128 -> C=64, no BN on input
  gemm_k<128, 64, 2, false><<<(N_NODES + 31) / 32, 256, 0, stream>>>(
      x, W1, b1, nullptr, nullptr, tbuf);
  agg_k<64, true><<<(N_NODES + 3) / 4, 256, 0, stream>>>(
      tbuf, csr_src, offsets, dis, selfn, hbuf, part1);
  bnfinal_k<<<1, 64, 0, stream>>>(part1, g1, be1, scale1, shift1);

  // layer 2: K=64 -> C=64, BN+ReLU fused into A staging
  gemm_k<64, 64, 4, true><<<(N_NODES + 63) / 64, 256, 0, stream>>>(
      hbuf, W2, b2, scale1, shift1, tbuf);
  agg_k<64, true><<<(N_NODES + 3) / 4, 256, 0, stream>>>(
      tbuf, csr_src, offsets, dis, selfn, hbuf, part2);
  bnfinal_k<<<1, 64, 0, stream>>>(part2, g2, be2, scale2, shift2);

  // layer 3: K=64 -> C=40, BN+ReLU fused; aggregate straight to d_out
  gemm_k<64, 40, 4, true><<<(N_NODES + 99) / 100, 256, 0, stream>>>(
      hbuf, W3, b3, scale2, shift2, tbuf);
  agg_k<40, false><<<(N_NODES + 3) / 4, 256, 0, stream>>>(
      tbuf, csr_src, offsets, dis, selfn, out, nullptr);
}

// Round 2
// 707.246 us; speedup vs baseline: 1.1657x; 1.1657x over previous
//
#include <hip/hip_runtime.h>

#define N_NODES 100000
#define N_EDGES 1600000

static constexpr int SCAN_CHUNK = 1024;
static constexpr int NB_SCAN = (N_NODES + SCAN_CHUNK - 1) / SCAN_CHUNK; // 98

// ---------------- degree / CSR build ----------------

__global__ __launch_bounds__(256) void count_deg_k(const int* __restrict__ dst,
                                                   int* __restrict__ counts) {
  int e = blockIdx.x * 256 + threadIdx.x;
  if (e < N_EDGES) atomicAdd(&counts[dst[e]], 1);
}

__global__ __launch_bounds__(256) void node_init_k(const int* __restrict__ counts,
                                                   float* __restrict__ dis,
                                                   float* __restrict__ selfn) {
  int i = blockIdx.x * 256 + threadIdx.x;
  if (i < N_NODES) {
    float deg = (float)counts[i] + 1.0f;  // +1 self loop
    dis[i] = rsqrtf(deg);
    selfn[i] = 1.0f / deg;
  }
}

__global__ __launch_bounds__(256) void scanA_k(const int* __restrict__ counts,
                                               int* __restrict__ blockSums) {
  __shared__ int sm[256];
  int b = blockIdx.x;
  int s = 0;
  for (int j = 0; j < 4; ++j) {
    int i = b * SCAN_CHUNK + j * 256 + threadIdx.x;
    if (i < N_NODES) s += counts[i];
  }
  sm[threadIdx.x] = s;
  __syncthreads();
  for (int off = 128; off > 0; off >>= 1) {
    if (threadIdx.x < off) sm[threadIdx.x] += sm[threadIdx.x + off];
    __syncthreads();
  }
  if (threadIdx.x == 0) blockSums[b] = sm[0];
}

__global__ void scanB_k(const int* __restrict__ blockSums,
                        int* __restrict__ blockOffs,
                        int* __restrict__ offsets) {
  __shared__ int sm[128];
  int t = threadIdx.x;  // blockDim = 128
  int v = (t < NB_SCAN) ? blockSums[t] : 0;
  sm[t] = v;
  __syncthreads();
  for (int off = 1; off < 128; off <<= 1) {
    int add = (t >= off) ? sm[t - off] : 0;
    __syncthreads();
    sm[t] += add;
    __syncthreads();
  }
  if (t < NB_SCAN) blockOffs[t] = sm[t] - v;  // exclusive
  if (t == 0) offsets[N_NODES] = N_EDGES;
}

__global__ __launch_bounds__(256) void scanC_k(const int* __restrict__ counts,
                                               const int* __restrict__ blockOffs,
                                               int* __restrict__ offsets,
                                               int* __restrict__ cursor) {
  __shared__ int sm[256];
  int b = blockIdx.x;
  int base = b * SCAN_CHUNK + threadIdx.x * 4;
  int v[4];
  int s = 0;
  for (int j = 0; j < 4; ++j) {
    int i = base + j;
    v[j] = (i < N_NODES) ? counts[i] : 0;
    s += v[j];
  }
  sm[threadIdx.x] = s;
  __syncthreads();
  for (int off = 1; off < 256; off <<= 1) {
    int add = (threadIdx.x >= off) ? sm[threadIdx.x - off] : 0;
    __syncthreads();
    sm[threadIdx.x] += add;
    __syncthreads();
  }
  int ex = blockOffs[b] + sm[threadIdx.x] - s;  // exclusive prefix for this thread
  for (int j = 0; j < 4; ++j) {
    int i = base + j;
    if (i < N_NODES) { offsets[i] = ex; cursor[i] = ex; }
    ex += v[j];
  }
}

__global__ __launch_bounds__(256) void fill_k(const int* __restrict__ src,
                                              const int* __restrict__ dst,
                                              int* __restrict__ cursor,
                                              int* __restrict__ csr_src) {
  int e = blockIdx.x * 256 + threadIdx.x;
  if (e < N_EDGES) {
    int d = dst[e];
    int p = atomicAdd(&cursor[d], 1);
    csr_src[p] = src[e];
  }
}

// ---------------- GEMM: out[N,C] = act(A)[N,K] @ W[K,C] + bias ----------------
// act = identity (BN=false) or relu(a*scale[k]+shift[k]) (BN=true), fused at staging.

template <int K, int C, int RPT, bool BN>
__global__ __launch_bounds__(256) void gemm_k(const float* __restrict__ A,
                                              const float* __restrict__ W,
                                              const float* __restrict__ bias,
                                              const float* __restrict__ scale,
                                              const float* __restrict__ shift,
                                              float* __restrict__ out) {
  constexpr int CQ = C / 4;        // float4 channel groups
  constexpr int TR = 256 / CQ;     // thread row-slots (floor)
  constexpr int ROWS = TR * RPT;   // rows per block
  __shared__ __align__(16) float Wl[K * C];
  __shared__ __align__(16) float Al[ROWS * K];
  const int tid = threadIdx.x;
  for (int i = tid; i < K * C; i += 256) Wl[i] = W[i];
  const int row0 = blockIdx.x * ROWS;
  for (int i = tid; i < ROWS * K; i += 256) {
    int r = i / K, k = i - r * K;
    int gr = row0 + r;
    float v = 0.f;
    if (gr < N_NODES) {
      v = A[(size_t)gr * K + k];
      if (BN) v = fmaxf(fmaf(v, scale[k], shift[k]), 0.f);
    }
    Al[i] = v;
  }
  __syncthreads();
  const int cq = tid % CQ;
  const int rs = tid / CQ;
  if (rs >= TR) return;  // only possible when 256 % CQ != 0 (C=40); no further barriers
  const float4* W4 = (const float4*)Wl;
  const float4* A4 = (const float4*)Al;
  float4 acc[RPT];
#pragma unroll
  for (int i = 0; i < RPT; ++i) acc[i] = make_float4(0.f, 0.f, 0.f, 0.f);
#pragma unroll 4
  for (int k4 = 0; k4 < K / 4; ++k4) {
    float4 w0 = W4[(4 * k4 + 0) * CQ + cq];
    float4 w1 = W4[(4 * k4 + 1) * CQ + cq];
    float4 w2 = W4[(4 * k4 + 2) * CQ + cq];
    float4 w3 = W4[(4 * k4 + 3) * CQ + cq];
#pragma unroll
    for (int i = 0; i < RPT; ++i) {
      float4 a = A4[(rs * RPT + i) * (K / 4) + k4];
      acc[i].x = fmaf(a.x, w0.x, acc[i].x); acc[i].y = fmaf(a.x, w0.y, acc[i].y);
      acc[i].z = fmaf(a.x, w0.z, acc[i].z); acc[i].w = fmaf(a.x, w0.w, acc[i].w);
      acc[i].x = fmaf(a.y, w1.x, acc[i].x); acc[i].y = fmaf(a.y, w1.y, acc[i].y);
      acc[i].z = fmaf(a.y, w1.z, acc[i].z); acc[i].w = fmaf(a.y, w1.w, acc[i].w);
      acc[i].x = fmaf(a.z, w2.x, acc[i].x); acc[i].y = fmaf(a.z, w2.y, acc[i].y);
      acc[i].z = fmaf(a.z, w2.z, acc[i].z); acc[i].w = fmaf(a.z, w2.w, acc[i].w);
      acc[i].x = fmaf(a.w, w3.x, acc[i].x); acc[i].y = fmaf(a.w, w3.y, acc[i].y);
      acc[i].z = fmaf(a.w, w3.z, acc[i].z); acc[i].w = fmaf(a.w, w3.w, acc[i].w);
    }
  }
  float4 b4 = ((const float4*)bias)[cq];
#pragma unroll
  for (int i = 0; i < RPT; ++i) {
    int gr = row0 + rs * RPT + i;
    if (gr < N_NODES) {
      float4 o = make_float4(acc[i].x + b4.x, acc[i].y + b4.y,
                             acc[i].z + b4.z, acc[i].w + b4.w);
      *((float4*)(out + (size_t)gr * C) + cq) = o;
    }
  }
}

// ---------------- aggregation: out[n] = dis[n]*sum_{e:dst=n} t[src_e]*dis[src_e] + t[n]*selfn[n]
// one wave per node, lane = channel. Edge indices/weights are broadcast to
// SGPRs via v_readlane (wave-uniform loop index) -> saddr gathers; 4-deep
// unroll with 4 independent accumulators keeps 4 gathers in flight.

template <int C, bool STATS>
__global__ __launch_bounds__(256) void agg_k(const float* __restrict__ t,
                                             const int* __restrict__ csr,
                                             const int* __restrict__ offs,
                                             const float* __restrict__ dis,
                                             const float* __restrict__ selfn,
                                             float* __restrict__ out,
                                             float* __restrict__ part) {
  __shared__ float s_sum[64];
  __shared__ float s_sq[64];
  if (STATS) {
    if (threadIdx.x < 64) { s_sum[threadIdx.x] = 0.f; s_sq[threadIdx.x] = 0.f; }
    __syncthreads();
  }
  const int lane = threadIdx.x & 63;
  const int node = blockIdx.x * 4 + (threadIdx.x >> 6);
  float v = 0.f;
  if (node < N_NODES) {
    const int beg = offs[node], end = offs[node + 1];
    float a0 = 0.f, a1 = 0.f, a2 = 0.f, a3 = 0.f;
    for (int base = beg; base < end; base += 64) {
      const int m = min(64, end - base);
      int sl = 0; int wl = 0;
      if (lane < m) { sl = csr[base + lane]; wl = __float_as_int(dis[sl]); }
      int j = 0;
      for (; j + 4 <= m; j += 4) {
        const int s0 = __builtin_amdgcn_readlane(sl, j);
        const int s1 = __builtin_amdgcn_readlane(sl, j + 1);
        const int s2 = __builtin_amdgcn_readlane(sl, j + 2);
        const int s3 = __builtin_amdgcn_readlane(sl, j + 3);
        const float w0 = __int_as_float(__builtin_amdgcn_readlane(wl, j));
        const float w1 = __int_as_float(__builtin_amdgcn_readlane(wl, j + 1));
        const float w2 = __int_as_float(__builtin_amdgcn_readlane(wl, j + 2));
        const float w3 = __int_as_float(__builtin_amdgcn_readlane(wl, j + 3));
        if (lane < C) {
          const float t0 = t[(size_t)s0 * C + lane];
          const float t1 = t[(size_t)s1 * C + lane];
          const float t2 = t[(size_t)s2 * C + lane];
          const float t3 = t[(size_t)s3 * C + lane];
          a0 = fmaf(t0, w0, a0);
          a1 = fmaf(t1, w1, a1);
          a2 = fmaf(t2, w2, a2);
          a3 = fmaf(t3, w3, a3);
        }
      }
      for (; j < m; ++j) {
        const int s0 = __builtin_amdgcn_readlane(sl, j);
        const float w0 = __int_as_float(__builtin_amdgcn_readlane(wl, j));
        if (lane < C) a0 = fmaf(t[(size_t)s0 * C + lane], w0, a0);
      }
    }
    if (lane < C) {
      const float acc = (a0 + a1) + (a2 + a3);
      v = fmaf(dis[node], acc, t[(size_t)node * C + lane] * selfn[node]);
      out[(size_t)node * C + lane] = v;
    }
  }
  if (STATS) {
    atomicAdd(&s_sum[lane], v);
    atomicAdd(&s_sq[lane], v * v);
    __syncthreads();
    if (threadIdx.x < 128) {
      const int c = threadIdx.x & 63;
      const float val = (threadIdx.x < 64) ? s_sum[c] : s_sq[c];
      atomicAdd(&part[(blockIdx.x & 63) * 128 + (threadIdx.x < 64 ? c : 64 + c)], val);
    }
  }
}

__global__ void bnfinal_k(const float* __restrict__ part, const float* __restrict__ g,
                          const float* __restrict__ be, float* __restrict__ scale,
                          float* __restrict__ shift) {
  const int c = threadIdx.x;  // 64 threads
  float s = 0.f, q = 0.f;
  for (int b = 0; b < 64; ++b) { s += part[b * 128 + c]; q += part[b * 128 + 64 + c]; }
  const float inv = 1.0f / (float)N_NODES;
  const float mu = s * inv;
  const float var = q * inv - mu * mu;
  const float sc = g[c] * rsqrtf(var + 1e-5f);
  scale[c] = sc;
  shift[c] = fmaf(-mu, sc, be[c]);
}

// ---------------- launch ----------------

extern "C" void kernel_launch(void* const* d_in, const int* in_sizes, int n_in,
                              void* d_out, int out_size, void* d_ws, size_t ws_size,
                              hipStream_t stream) {
  const float* x   = (const float*)d_in[0];
  const int*   ei  = (const int*)d_in[1];
  const float* W1  = (const float*)d_in[2];
  const float* b1  = (const float*)d_in[3];
  const float* g1  = (const float*)d_in[4];
  const float* be1 = (const float*)d_in[5];
  const float* W2  = (const float*)d_in[6];
  const float* b2  = (const float*)d_in[7];
  const float* g2  = (const float*)d_in[8];
  const float* be2 = (const float*)d_in[9];
  const float* W3  = (const float*)d_in[10];
  const float* b3  = (const float*)d_in[11];
  float* out = (float*)d_out;
  const int* src = ei;
  const int* dst = ei + N_EDGES;

  char* ws = (char*)d_ws;
  size_t o = 0;
  auto alloc = [&](size_t bytes) -> char* {
    char* p = ws + o;
    o += (bytes + 255) & ~(size_t)255;
    return p;
  };
  int*   counts    = (int*)alloc((size_t)N_NODES * 4);
  int*   offsets   = (int*)alloc(((size_t)N_NODES + 1) * 4);
  int*   cursor    = (int*)alloc((size_t)N_NODES * 4);
  int*   csr_src   = (int*)alloc((size_t)N_EDGES * 4);
  float* dis       = (float*)alloc((size_t)N_NODES * 4);
  float* selfn     = (float*)alloc((size_t)N_NODES * 4);
  int*   blockSums = (int*)alloc(NB_SCAN * 4);
  int*   blockOffs = (int*)alloc(NB_SCAN * 4);
  float* part1     = (float*)alloc(64 * 128 * 4);  // 32 KiB, 256-aligned
  float* part2     = (float*)alloc(64 * 128 * 4);  // contiguous with part1
  float* scale1    = (float*)alloc(64 * 4);
  float* shift1    = (float*)alloc(64 * 4);
  float* scale2    = (float*)alloc(64 * 4);
  float* shift2    = (float*)alloc(64 * 4);
  float* tbuf      = (float*)alloc((size_t)N_NODES * 64 * 4);
  float* hbuf      = (float*)alloc((size_t)N_NODES * 64 * 4);

  hipMemsetAsync(counts, 0, (size_t)N_NODES * 4, stream);
  hipMemsetAsync(part1, 0, 2 * 64 * 128 * 4, stream);  // part1+part2

  count_deg_k<<<(N_EDGES + 255) / 256, 256, 0, stream>>>(dst, counts);
  node_init_k<<<(N_NODES + 255) / 256, 256, 0, stream>>>(counts, dis, selfn);
  scanA_k<<<NB_SCAN, 256, 0, stream>>>(counts, blockSums);
  scanB_k<<<1, 128, 0, stream>>>(blockSums, blockOffs, offsets);
  scanC_k<<<NB_SCAN, 256, 0, stream>>>(counts, blockOffs, offsets, cursor);
  fill_k<<<(N_EDGES + 255) / 256, 256, 0, stream>>>(src, dst, cursor, csr_src);

  // layer 1: K=128 -> C=64, no BN on input
  gemm_k<128, 64, 2, false><<<(N_NODES + 31) / 32, 256, 0, stream>>>(
      x, W1, b1, nullptr, nullptr, tbuf);
  agg_k<64, true><<<(N_NODES + 3) / 4, 256, 0, stream>>>(
      tbuf, csr_src, offsets, dis, selfn, hbuf, part1);
  bnfinal_k<<<1, 64, 0, stream>>>(part1, g1, be1, scale1, shift1);

  // layer 2: K=64 -> C=64, BN+ReLU fused into A staging
  gemm_k<64, 64, 4, true><<<(N_NODES + 63) / 64, 256, 0, stream>>>(
      hbuf, W2, b2, scale1, shift1, tbuf);
  agg_k<64, true><<<(N_NODES + 3) / 4, 256, 0, stream>>>(
      tbuf, csr_src, offsets, dis, selfn, hbuf, part2);
  bnfinal_k<<<1, 64, 0, stream>>>(part2, g2, be2, scale2, shift2);

  // layer 3: K=64 -> C=40, BN+ReLU fused; aggregate straight to d_out
  gemm_k<64, 40, 4, true><<<(N_NODES + 99) / 100, 256, 0, stream>>>(
      hbuf, W3, b3, scale2, shift2, tbuf);
  agg_k<40, false><<<(N_NODES + 3) / 4, 256, 0, stream>>>(
      tbuf, csr_src, offsets, dis, selfn, out, nullptr);
}

// Round 3
// 571.495 us; speedup vs baseline: 1.4426x; 1.2375x over previous
//
#include <hip/hip_runtime.h>

#define N_NODES 100000
#define N_EDGES 1600000
#define NBKT 391            // bucket = dst >> 8, 256 nodes per bucket
#define EPB 4096            // edges per block in bucket passes
#define NBLK_E ((N_EDGES + EPB - 1) / EPB)  // 391

// ---------------- CSR build: two-level bucket counting sort ----------------

__global__ __launch_bounds__(256) void bucket_count_k(const int* __restrict__ dst,
                                                      int* __restrict__ gCount) {
  __shared__ int h[NBKT];
  for (int i = threadIdx.x; i < NBKT; i += 256) h[i] = 0;
  __syncthreads();
  const int e0 = blockIdx.x * EPB;
  const int eN = min(EPB, N_EDGES - e0);
  for (int i = threadIdx.x; i < eN; i += 256) atomicAdd(&h[dst[e0 + i] >> 8], 1);
  __syncthreads();
  for (int i = threadIdx.x; i < NBKT; i += 256)
    if (h[i]) atomicAdd(&gCount[i], h[i]);
}

__global__ void bucket_scan_k(const int* __restrict__ gCount,
                              int* __restrict__ gBase,
                              int* __restrict__ gCursor,
                              int* __restrict__ offsets) {
  __shared__ int sm[512];
  const int t = threadIdx.x;  // 256
  const int c0 = (t < NBKT) ? gCount[t] : 0;
  const int c1 = (t + 256 < NBKT) ? gCount[t + 256] : 0;
  sm[t] = c0; sm[t + 256] = c1;
  __syncthreads();
  for (int off = 1; off < 512; off <<= 1) {
    const int v0 = (t >= off) ? sm[t - off] : 0;
    const int v1 = (t + 256 >= off) ? sm[t + 256 - off] : 0;
    __syncthreads();
    sm[t] += v0; sm[t + 256] += v1;
    __syncthreads();
  }
  if (t < NBKT)       { const int b = sm[t] - c0;       gBase[t] = b;       gCursor[t] = b; }
  if (t + 256 < NBKT) { const int b = sm[t + 256] - c1; gBase[t + 256] = b; gCursor[t + 256] = b; }
  if (t == 0) { gBase[NBKT] = N_EDGES; offsets[N_NODES] = N_EDGES; }
}

// chunk -> LDS counting-sort by bucket -> coalesced run writes into ebuf
__global__ __launch_bounds__(256) void bucket_scatter_k(const int* __restrict__ src,
                                                        const int* __restrict__ dst,
                                                        int* __restrict__ gCursor,
                                                        uint2* __restrict__ ebuf) {
  __shared__ int cnt[NBKT];
  __shared__ int inc[512];
  __shared__ int gb[NBKT];
  __shared__ int cur[NBKT];
  __shared__ uint2 st[EPB];
  const int t = threadIdx.x;
  for (int i = t; i < NBKT; i += 256) cnt[i] = 0;
  __syncthreads();
  const int e0 = blockIdx.x * EPB;
  const int eN = min(EPB, N_EDGES - e0);
  for (int i = t; i < eN; i += 256) atomicAdd(&cnt[dst[e0 + i] >> 8], 1);
  __syncthreads();
  const int c0 = (t < NBKT) ? cnt[t] : 0;
  const int c1 = (t + 256 < NBKT) ? cnt[t + 256] : 0;
  inc[t] = c0; inc[t + 256] = c1;
  __syncthreads();
  for (int off = 1; off < 512; off <<= 1) {
    const int v0 = (t >= off) ? inc[t - off] : 0;
    const int v1 = (t + 256 >= off) ? inc[t + 256 - off] : 0;
    __syncthreads();
    inc[t] += v0; inc[t + 256] += v1;
    __syncthreads();
  }
  if (t < NBKT) {
    if (c0) gb[t] = atomicAdd(&gCursor[t], c0);
    cur[t] = inc[t] - c0;
  }
  if (t + 256 < NBKT) {
    if (c1) gb[t + 256] = atomicAdd(&gCursor[t + 256], c1);
    cur[t + 256] = inc[t + 256] - c1;
  }
  __syncthreads();
  for (int i = t; i < eN; i += 256) {
    const int d = dst[e0 + i];
    const int b = d >> 8;
    const int p = atomicAdd(&cur[b], 1);
    st[p] = make_uint2((unsigned)src[e0 + i], (unsigned)d);
  }
  __syncthreads();
  for (int i = t; i < eN; i += 256) {
    const uint2 e = st[i];
    const int b = (int)(e.y >> 8);
    const int excl = inc[b] - cnt[b];
    ebuf[gb[b] + (i - excl)] = e;   // adjacent i in a run -> adjacent addrs
  }
}

// one block per bucket: per-node count/scan/scatter in LDS; emits offsets,
// degree-derived dis/selfn, and csr_src (stores confined to one CU's region)
__global__ __launch_bounds__(256) void csr_build_k(const uint2* __restrict__ ebuf,
                                                   const int* __restrict__ gBase,
                                                   int* __restrict__ offsets,
                                                   int* __restrict__ csr_src,
                                                   float* __restrict__ dis,
                                                   float* __restrict__ selfn) {
  __shared__ int cnt[256];
  __shared__ int inc[256];
  __shared__ int cur[256];
  const int t = threadIdx.x;
  const int b = blockIdx.x;
  const int ebeg = gBase[b], eend = gBase[b + 1];
  cnt[t] = 0;
  __syncthreads();
  for (int e = ebeg + t; e < eend; e += 256) atomicAdd(&cnt[ebuf[e].y & 255], 1);
  __syncthreads();
  const int c = cnt[t];
  inc[t] = c;
  __syncthreads();
  for (int off = 1; off < 256; off <<= 1) {
    const int v = (t >= off) ? inc[t - off] : 0;
    __syncthreads();
    inc[t] += v;
    __syncthreads();
  }
  const int node = (b << 8) + t;
  const int goff = ebeg + inc[t] - c;
  cur[t] = goff;
  if (node < N_NODES) {
    offsets[node] = goff;
    const float deg = (float)c + 1.0f;  // +1 self loop
    dis[node] = rsqrtf(deg);
    selfn[node] = 1.0f / deg;
  }
  __syncthreads();
  for (int e = ebeg + t; e < eend; e += 256) {
    const uint2 ed = ebuf[e];
    const int p = atomicAdd(&cur[ed.y & 255], 1);
    csr_src[p] = (int)ed.x;
  }
}

// ---------------- GEMM: out[N,C] = act(A)[N,K] @ W[K,C] + bias ----------------
// act = identity (BN=false) or relu(a*scale[k]+shift[k]) (BN=true), fused at staging.

template <int K, int C, int RPT, bool BN>
__global__ __launch_bounds__(256) void gemm_k(const float* __restrict__ A,
                                              const float* __restrict__ W,
                                              const float* __restrict__ bias,
                                              const float* __restrict__ scale,
                                              const float* __restrict__ shift,
                                              float* __restrict__ out) {
  constexpr int CQ = C / 4;        // float4 channel groups
  constexpr int TR = 256 / CQ;     // thread row-slots (floor)
  constexpr int ROWS = TR * RPT;   // rows per block
  __shared__ __align__(16) float Wl[K * C];
  __shared__ __align__(16) float Al[ROWS * K];
  const int tid = threadIdx.x;
  for (int i = tid; i < K * C; i += 256) Wl[i] = W[i];
  const int row0 = blockIdx.x * ROWS;
  for (int i = tid; i < ROWS * K; i += 256) {
    int r = i / K, k = i - r * K;
    int gr = row0 + r;
    float v = 0.f;
    if (gr < N_NODES) {
      v = A[(size_t)gr * K + k];
      if (BN) v = fmaxf(fmaf(v, scale[k], shift[k]), 0.f);
    }
    Al[i] = v;
  }
  __syncthreads();
  const int cq = tid % CQ;
  const int rs = tid / CQ;
  if (rs >= TR) return;  // only possible when 256 % CQ != 0 (C=40); no further barriers
  const float4* W4 = (const float4*)Wl;
  const float4* A4 = (const float4*)Al;
  float4 acc[RPT];
#pragma unroll
  for (int i = 0; i < RPT; ++i) acc[i] = make_float4(0.f, 0.f, 0.f, 0.f);
#pragma unroll 4
  for (int k4 = 0; k4 < K / 4; ++k4) {
    float4 w0 = W4[(4 * k4 + 0) * CQ + cq];
    float4 w1 = W4[(4 * k4 + 1) * CQ + cq];
    float4 w2 = W4[(4 * k4 + 2) * CQ + cq];
    float4 w3 = W4[(4 * k4 + 3) * CQ + cq];
#pragma unroll
    for (int i = 0; i < RPT; ++i) {
      float4 a = A4[(rs * RPT + i) * (K / 4) + k4];
      acc[i].x = fmaf(a.x, w0.x, acc[i].x); acc[i].y = fmaf(a.x, w0.y, acc[i].y);
      acc[i].z = fmaf(a.x, w0.z, acc[i].z); acc[i].w = fmaf(a.x, w0.w, acc[i].w);
      acc[i].x = fmaf(a.y, w1.x, acc[i].x); acc[i].y = fmaf(a.y, w1.y, acc[i].y);
      acc[i].z = fmaf(a.y, w1.z, acc[i].z); acc[i].w = fmaf(a.y, w1.w, acc[i].w);
      acc[i].x = fmaf(a.z, w2.x, acc[i].x); acc[i].y = fmaf(a.z, w2.y, acc[i].y);
      acc[i].z = fmaf(a.z, w2.z, acc[i].z); acc[i].w = fmaf(a.z, w2.w, acc[i].w);
      acc[i].x = fmaf(a.w, w3.x, acc[i].x); acc[i].y = fmaf(a.w, w3.y, acc[i].y);
      acc[i].z = fmaf(a.w, w3.z, acc[i].z); acc[i].w = fmaf(a.w, w3.w, acc[i].w);
    }
  }
  float4 b4 = ((const float4*)bias)[cq];
#pragma unroll
  for (int i = 0; i < RPT; ++i) {
    int gr = row0 + rs * RPT + i;
    if (gr < N_NODES) {
      float4 o = make_float4(acc[i].x + b4.x, acc[i].y + b4.y,
                             acc[i].z + b4.z, acc[i].w + b4.w);
      *((float4*)(out + (size_t)gr * C) + cq) = o;
    }
  }
}

// ---------------- aggregation: out[n] = dis[n]*sum_{e:dst=n} t[src_e]*dis[src_e] + t[n]*selfn[n]
// one wave per node, lane = channel. Edge indices/weights broadcast via
// v_readlane (SGPR) -> saddr gathers; 4 independent accumulators for MLP.

template <int C, bool STATS>
__global__ __launch_bounds__(256) void agg_k(const float* __restrict__ t,
                                             const int* __restrict__ csr,
                                             const int* __restrict__ offs,
                                             const float* __restrict__ dis,
                                             const float* __restrict__ selfn,
                                             float* __restrict__ out,
                                             float* __restrict__ part) {
  __shared__ float s_sum[64];
  __shared__ float s_sq[64];
  if (STATS) {
    if (threadIdx.x < 64) { s_sum[threadIdx.x] = 0.f; s_sq[threadIdx.x] = 0.f; }
    __syncthreads();
  }
  const int lane = threadIdx.x & 63;
  const int node = blockIdx.x * 4 + (threadIdx.x >> 6);
  float v = 0.f;
  if (node < N_NODES) {
    const int beg = offs[node], end = offs[node + 1];
    float a0 = 0.f, a1 = 0.f, a2 = 0.f, a3 = 0.f;
    for (int base = beg; base < end; base += 64) {
      const int m = min(64, end - base);
      int sl = 0; int wl = 0;
      if (lane < m) { sl = csr[base + lane]; wl = __float_as_int(dis[sl]); }
      int j = 0;
      for (; j + 4 <= m; j += 4) {
        const int s0 = __builtin_amdgcn_readlane(sl, j);
        const int s1 = __builtin_amdgcn_readlane(sl, j + 1);
        const int s2 = __builtin_amdgcn_readlane(sl, j + 2);
        const int s3 = __builtin_amdgcn_readlane(sl, j + 3);
        const float w0 = __int_as_float(__builtin_amdgcn_readlane(wl, j));
        const float w1 = __int_as_float(__builtin_amdgcn_readlane(wl, j + 1));
        const float w2 = __int_as_float(__builtin_amdgcn_readlane(wl, j + 2));
        const float w3 = __int_as_float(__builtin_amdgcn_readlane(wl, j + 3));
        if (lane < C) {
          const float t0 = t[(size_t)s0 * C + lane];
          const float t1 = t[(size_t)s1 * C + lane];
          const float t2 = t[(size_t)s2 * C + lane];
          const float t3 = t[(size_t)s3 * C + lane];
          a0 = fmaf(t0, w0, a0);
          a1 = fmaf(t1, w1, a1);
          a2 = fmaf(t2, w2, a2);
          a3 = fmaf(t3, w3, a3);
        }
      }
      for (; j < m; ++j) {
        const int s0 = __builtin_amdgcn_readlane(sl, j);
        const float w0 = __int_as_float(__builtin_amdgcn_readlane(wl, j));
        if (lane < C) a0 = fmaf(t[(size_t)s0 * C + lane], w0, a0);
      }
    }
    if (lane < C) {
      const float acc = (a0 + a1) + (a2 + a3);
      v = fmaf(dis[node], acc, t[(size_t)node * C + lane] * selfn[node]);
      out[(size_t)node * C + lane] = v;
    }
  }
  if (STATS) {
    atomicAdd(&s_sum[lane], v);
    atomicAdd(&s_sq[lane], v * v);
    __syncthreads();
    if (threadIdx.x < 128) {
      const int c = threadIdx.x & 63;
      const float val = (threadIdx.x < 64) ? s_sum[c] : s_sq[c];
      atomicAdd(&part[(blockIdx.x & 63) * 128 + (threadIdx.x < 64 ? c : 64 + c)], val);
    }
  }
}

__global__ void bnfinal_k(const float* __restrict__ part, const float* __restrict__ g,
                          const float* __restrict__ be, float* __restrict__ scale,
                          float* __restrict__ shift) {
  const int c = threadIdx.x;  // 64 threads
  float s = 0.f, q = 0.f;
  for (int b = 0; b < 64; ++b) { s += part[b * 128 + c]; q += part[b * 128 + 64 + c]; }
  const float inv = 1.0f / (float)N_NODES;
  const float mu = s * inv;
  const float var = q * inv - mu * mu;
  const float sc = g[c] * rsqrtf(var + 1e-5f);
  scale[c] = sc;
  shift[c] = fmaf(-mu, sc, be[c]);
}

// ---------------- launch ----------------

extern "C" void kernel_launch(void* const* d_in, const int* in_sizes, int n_in,
                              void* d_out, int out_size, void* d_ws, size_t ws_size,
                              hipStream_t stream) {
  const float* x   = (const float*)d_in[0];
  const int*   ei  = (const int*)d_in[1];
  const float* W1  = (const float*)d_in[2];
  const float* b1  = (const float*)d_in[3];
  const float* g1  = (const float*)d_in[4];
  const float* be1 = (const float*)d_in[5];
  const float* W2  = (const float*)d_in[6];
  const float* b2  = (const float*)d_in[7];
  const float* g2  = (const float*)d_in[8];
  const float* be2 = (const float*)d_in[9];
  const float* W3  = (const float*)d_in[10];
  const float* b3  = (const float*)d_in[11];
  float* out = (float*)d_out;
  const int* src = ei;
  const int* dst = ei + N_EDGES;

  char* ws = (char*)d_ws;
  size_t o = 0;
  auto alloc = [&](size_t bytes) -> char* {
    char* p = ws + o;
    o += (bytes + 255) & ~(size_t)255;
    return p;
  };
  int*   gCount  = (int*)alloc((size_t)NBKT * 4);
  int*   gBase   = (int*)alloc(((size_t)NBKT + 1) * 4);
  int*   gCursor = (int*)alloc((size_t)NBKT * 4);
  int*   offsets = (int*)alloc(((size_t)N_NODES + 1) * 4);
  int*   csr_src = (int*)alloc((size_t)N_EDGES * 4);
  float* dis     = (float*)alloc((size_t)N_NODES * 4);
  float* selfn   = (float*)alloc((size_t)N_NODES * 4);
  float* part1   = (float*)alloc(64 * 128 * 4);  // 32 KiB
  float* part2   = (float*)alloc(64 * 128 * 4);  // contiguous with part1
  float* scale1  = (float*)alloc(64 * 4);
  float* shift1  = (float*)alloc(64 * 4);
  float* scale2  = (float*)alloc(64 * 4);
  float* shift2  = (float*)alloc(64 * 4);
  float* tbuf    = (float*)alloc((size_t)N_NODES * 64 * 4);
  float* hbuf    = (float*)alloc((size_t)N_NODES * 64 * 4);
  // ebuf (12.8 MB) aliases tbuf (25.6 MB): CSR build completes before gemm1
  // writes tbuf; same-stream ordering makes this safe.
  uint2* ebuf = (uint2*)tbuf;

  hipMemsetAsync(gCount, 0, (size_t)NBKT * 4, stream);
  hipMemsetAsync(part1, 0, 2 * 64 * 128 * 4, stream);  // part1+part2

  bucket_count_k<<<NBLK_E, 256, 0, stream>>>(dst, gCount);
  bucket_scan_k<<<1, 256, 0, stream>>>(gCount, gBase, gCursor, offsets);
  bucket_scatter_k<<<NBLK_E, 256, 0, stream>>>(src, dst, gCursor, ebuf);
  csr_build_k<<<NBKT, 256, 0, stream>>>(ebuf, gBase, offsets, csr_src, dis, selfn);

  // layer 1: K=128 -> C=64, no BN on input
  gemm_k<128, 64, 2, false><<<(N_NODES + 31) / 32, 256, 0, stream>>>(
      x, W1, b1, nullptr, nullptr, tbuf);
  agg_k<64, true><<<(N_NODES + 3) / 4, 256, 0, stream>>>(
      tbuf, csr_src, offsets, dis, selfn, hbuf, part1);
  bnfinal_k<<<1, 64, 0, stream>>>(part1, g1, be1, scale1, shift1);

  // layer 2: K=64 -> C=64, BN+ReLU fused into A staging
  gemm_k<64, 64, 4, true><<<(N_NODES + 63) / 64, 256, 0, stream>>>(
      hbuf, W2, b2, scale1, shift1, tbuf);
  agg_k<64, true><<<(N_NODES + 3) / 4, 256, 0, stream>>>(
      tbuf, csr_src, offsets, dis, selfn, hbuf, part2);
  bnfinal_k<<<1, 64, 0, stream>>>(part2, g2, be2, scale2, shift2);

  // layer 3: K=64 -> C=40, BN+ReLU fused; aggregate straight to d_out
  gemm_k<64, 40, 4, true><<<(N_NODES + 99) / 100, 256, 0, stream>>>(
      hbuf, W3, b3, scale2, shift2, tbuf);
  agg_k<40, false><<<(N_NODES + 3) / 4, 256, 0, stream>>>(
      tbuf, csr_src, offsets, dis, selfn, out, nullptr);
}

// Round 4
// 542.031 us; speedup vs baseline: 1.5210x; 1.0544x over previous
//
#include <hip/hip_runtime.h>

#define N_NODES 100000
#define N_EDGES 1600000
#define NBKT 391            // bucket = dst >> 8, 256 nodes per bucket
#define EPB 4096            // edges per block in bucket passes
#define NBLK_E ((N_EDGES + EPB - 1) / EPB)  // 391

// ---------------- CSR build: two-level bucket counting sort ----------------

__global__ __launch_bounds__(256) void bucket_count_k(const int* __restrict__ dst,
                                                      int* __restrict__ gCount) {
  __shared__ int h[NBKT];
  for (int i = threadIdx.x; i < NBKT; i += 256) h[i] = 0;
  __syncthreads();
  const int e0 = blockIdx.x * EPB;
  const int eN = min(EPB, N_EDGES - e0);
  for (int i = threadIdx.x; i < eN; i += 256) atomicAdd(&h[dst[e0 + i] >> 8], 1);
  __syncthreads();
  for (int i = threadIdx.x; i < NBKT; i += 256)
    if (h[i]) atomicAdd(&gCount[i], h[i]);
}

__global__ void bucket_scan_k(const int* __restrict__ gCount,
                              int* __restrict__ gBase,
                              int* __restrict__ gCursor,
                              int* __restrict__ offsets) {
  __shared__ int sm[512];
  const int t = threadIdx.x;  // 256
  const int c0 = (t < NBKT) ? gCount[t] : 0;
  const int c1 = (t + 256 < NBKT) ? gCount[t + 256] : 0;
  sm[t] = c0; sm[t + 256] = c1;
  __syncthreads();
  for (int off = 1; off < 512; off <<= 1) {
    const int v0 = (t >= off) ? sm[t - off] : 0;
    const int v1 = (t + 256 >= off) ? sm[t + 256 - off] : 0;
    __syncthreads();
    sm[t] += v0; sm[t + 256] += v1;
    __syncthreads();
  }
  if (t < NBKT)       { const int b = sm[t] - c0;       gBase[t] = b;       gCursor[t] = b; }
  if (t + 256 < NBKT) { const int b = sm[t + 256] - c1; gBase[t + 256] = b; gCursor[t + 256] = b; }
  if (t == 0) { gBase[NBKT] = N_EDGES; offsets[N_NODES] = N_EDGES; }
}

// chunk -> LDS counting-sort by bucket -> coalesced run writes into ebuf
__global__ __launch_bounds__(256) void bucket_scatter_k(const int* __restrict__ src,
                                                        const int* __restrict__ dst,
                                                        int* __restrict__ gCursor,
                                                        uint2* __restrict__ ebuf) {
  __shared__ int cnt[NBKT];
  __shared__ int inc[512];
  __shared__ int gb[NBKT];
  __shared__ int cur[NBKT];
  __shared__ uint2 st[EPB];
  const int t = threadIdx.x;
  for (int i = t; i < NBKT; i += 256) cnt[i] = 0;
  __syncthreads();
  const int e0 = blockIdx.x * EPB;
  const int eN = min(EPB, N_EDGES - e0);
  for (int i = t; i < eN; i += 256) atomicAdd(&cnt[dst[e0 + i] >> 8], 1);
  __syncthreads();
  const int c0 = (t < NBKT) ? cnt[t] : 0;
  const int c1 = (t + 256 < NBKT) ? cnt[t + 256] : 0;
  inc[t] = c0; inc[t + 256] = c1;
  __syncthreads();
  for (int off = 1; off < 512; off <<= 1) {
    const int v0 = (t >= off) ? inc[t - off] : 0;
    const int v1 = (t + 256 >= off) ? inc[t + 256 - off] : 0;
    __syncthreads();
    inc[t] += v0; inc[t + 256] += v1;
    __syncthreads();
  }
  if (t < NBKT) {
    if (c0) gb[t] = atomicAdd(&gCursor[t], c0);
    cur[t] = inc[t] - c0;
  }
  if (t + 256 < NBKT) {
    if (c1) gb[t + 256] = atomicAdd(&gCursor[t + 256], c1);
    cur[t + 256] = inc[t + 256] - c1;
  }
  __syncthreads();
  for (int i = t; i < eN; i += 256) {
    const int d = dst[e0 + i];
    const int b = d >> 8;
    const int p = atomicAdd(&cur[b], 1);
    st[p] = make_uint2((unsigned)src[e0 + i], (unsigned)d);
  }
  __syncthreads();
  for (int i = t; i < eN; i += 256) {
    const uint2 e = st[i];
    const int b = (int)(e.y >> 8);
    const int excl = inc[b] - cnt[b];
    ebuf[gb[b] + (i - excl)] = e;   // adjacent i in a run -> adjacent addrs
  }
}

// one block per bucket: per-node count/scan/scatter in LDS; emits offsets,
// degree-derived dis/selfn, and csr_src (stores confined to one CU's region)
__global__ __launch_bounds__(256) void csr_build_k(const uint2* __restrict__ ebuf,
                                                   const int* __restrict__ gBase,
                                                   int* __restrict__ offsets,
                                                   int* __restrict__ csr_src,
                                                   float* __restrict__ dis,
                                                   float* __restrict__ selfn) {
  __shared__ int cnt[256];
  __shared__ int inc[256];
  __shared__ int cur[256];
  const int t = threadIdx.x;
  const int b = blockIdx.x;
  const int ebeg = gBase[b], eend = gBase[b + 1];
  cnt[t] = 0;
  __syncthreads();
  for (int e = ebeg + t; e < eend; e += 256) atomicAdd(&cnt[ebuf[e].y & 255], 1);
  __syncthreads();
  const int c = cnt[t];
  inc[t] = c;
  __syncthreads();
  for (int off = 1; off < 256; off <<= 1) {
    const int v = (t >= off) ? inc[t - off] : 0;
    __syncthreads();
    inc[t] += v;
    __syncthreads();
  }
  const int node = (b << 8) + t;
  const int goff = ebeg + inc[t] - c;
  cur[t] = goff;
  if (node < N_NODES) {
    offsets[node] = goff;
    const float deg = (float)c + 1.0f;  // +1 self loop
    dis[node] = rsqrtf(deg);
    selfn[node] = 1.0f / deg;
  }
  __syncthreads();
  for (int e = ebeg + t; e < eend; e += 256) {
    const uint2 ed = ebuf[e];
    const int p = atomicAdd(&cur[ed.y & 255], 1);
    csr_src[p] = (int)ed.x;
  }
}

// ---------------- GEMM: out[N,C] = act(A)[N,K] @ W[K,C] + bias ----------------
// act = identity (BN=false) or relu(a*scale[k]+shift[k]) (BN=true), fused at staging.

template <int K, int C, int RPT, bool BN>
__global__ __launch_bounds__(256) void gemm_k(const float* __restrict__ A,
                                              const float* __restrict__ W,
                                              const float* __restrict__ bias,
                                              const float* __restrict__ scale,
                                              const float* __restrict__ shift,
                                              float* __restrict__ out) {
  constexpr int CQ = C / 4;        // float4 channel groups
  constexpr int TR = 256 / CQ;     // thread row-slots (floor)
  constexpr int ROWS = TR * RPT;   // rows per block
  __shared__ __align__(16) float Wl[K * C];
  __shared__ __align__(16) float Al[ROWS * K];
  const int tid = threadIdx.x;
  for (int i = tid; i < K * C; i += 256) Wl[i] = W[i];
  const int row0 = blockIdx.x * ROWS;
  for (int i = tid; i < ROWS * K; i += 256) {
    int r = i / K, k = i - r * K;
    int gr = row0 + r;
    float v = 0.f;
    if (gr < N_NODES) {
      v = A[(size_t)gr * K + k];
      if (BN) v = fmaxf(fmaf(v, scale[k], shift[k]), 0.f);
    }
    Al[i] = v;
  }
  __syncthreads();
  const int cq = tid % CQ;
  const int rs = tid / CQ;
  if (rs >= TR) return;  // only possible when 256 % CQ != 0 (C=40); no further barriers
  const float4* W4 = (const float4*)Wl;
  const float4* A4 = (const float4*)Al;
  float4 acc[RPT];
#pragma unroll
  for (int i = 0; i < RPT; ++i) acc[i] = make_float4(0.f, 0.f, 0.f, 0.f);
#pragma unroll 4
  for (int k4 = 0; k4 < K / 4; ++k4) {
    float4 w0 = W4[(4 * k4 + 0) * CQ + cq];
    float4 w1 = W4[(4 * k4 + 1) * CQ + cq];
    float4 w2 = W4[(4 * k4 + 2) * CQ + cq];
    float4 w3 = W4[(4 * k4 + 3) * CQ + cq];
#pragma unroll
    for (int i = 0; i < RPT; ++i) {
      float4 a = A4[(rs * RPT + i) * (K / 4) + k4];
      acc[i].x = fmaf(a.x, w0.x, acc[i].x); acc[i].y = fmaf(a.x, w0.y, acc[i].y);
      acc[i].z = fmaf(a.x, w0.z, acc[i].z); acc[i].w = fmaf(a.x, w0.w, acc[i].w);
      acc[i].x = fmaf(a.y, w1.x, acc[i].x); acc[i].y = fmaf(a.y, w1.y, acc[i].y);
      acc[i].z = fmaf(a.y, w1.z, acc[i].z); acc[i].w = fmaf(a.y, w1.w, acc[i].w);
      acc[i].x = fmaf(a.z, w2.x, acc[i].x); acc[i].y = fmaf(a.z, w2.y, acc[i].y);
      acc[i].z = fmaf(a.z, w2.z, acc[i].z); acc[i].w = fmaf(a.z, w2.w, acc[i].w);
      acc[i].x = fmaf(a.w, w3.x, acc[i].x); acc[i].y = fmaf(a.w, w3.y, acc[i].y);
      acc[i].z = fmaf(a.w, w3.z, acc[i].z); acc[i].w = fmaf(a.w, w3.w, acc[i].w);
    }
  }
  float4 b4 = ((const float4*)bias)[cq];
#pragma unroll
  for (int i = 0; i < RPT; ++i) {
    int gr = row0 + rs * RPT + i;
    if (gr < N_NODES) {
      float4 o = make_float4(acc[i].x + b4.x, acc[i].y + b4.y,
                             acc[i].z + b4.z, acc[i].w + b4.w);
      *((float4*)(out + (size_t)gr * C) + cq) = o;
    }
  }
}

// ---------------- aggregation ----------------
// out[n] = dis[n]*sum_{e:dst=n} t[src_e]*dis[src_e] + t[n]*selfn[n]
// One wave per node. Wave = NG groups x LPG lanes; each lane loads a float4,
// so one global_load_dwordx4 gathers NG edge-rows (1 KB for C=64). 4-deep
// unroll with 4 independent float4 accumulators => ~4 KB in flight per wave.

template <int C, int NG, int LPG, bool STATS>
__global__ __launch_bounds__(256) void agg_k(const float* __restrict__ t,
                                             const int* __restrict__ csr,
                                             const int* __restrict__ offs,
                                             const float* __restrict__ dis,
                                             const float* __restrict__ selfn,
                                             float* __restrict__ out,
                                             float* __restrict__ part) {
  __shared__ float s_sum[64];
  __shared__ float s_sq[64];
  if (STATS) {
    if (threadIdx.x < 64) { s_sum[threadIdx.x] = 0.f; s_sq[threadIdx.x] = 0.f; }
    __syncthreads();
  }
  const int lane = threadIdx.x & 63;
  const int node = blockIdx.x * 4 + (threadIdx.x >> 6);
  const int g = lane / LPG;        // group = which edge in a chunk
  const int c4 = lane - g * LPG;   // float4 slot within row
  const bool active = (g < NG);
  float4 v = make_float4(0.f, 0.f, 0.f, 0.f);
  if (node < N_NODES) {
    const int beg = offs[node], end = offs[node + 1];
    float4 a0 = make_float4(0.f, 0.f, 0.f, 0.f);
    float4 a1 = a0, a2 = a0, a3 = a0;
    const float* __restrict__ tc4 = t + c4 * 4;
    for (int base = beg; base < end; base += 64) {
      const int m = min(64, end - base);
      int sl = 0; float wl = 0.f;
      if (lane < m) { sl = csr[base + lane]; wl = dis[sl]; }
#define CHUNK(JJ, ACC) {                                              \
      const int idx = (JJ) + g;                                       \
      int s = __shfl(sl, idx);                                        \
      float w = __shfl(wl, idx);                                      \
      if (!active || idx >= m) { s = 0; w = 0.f; }                    \
      const float4 tv = *(const float4*)(tc4 + (size_t)s * C);        \
      ACC.x = fmaf(tv.x, w, ACC.x);                                   \
      ACC.y = fmaf(tv.y, w, ACC.y);                                   \
      ACC.z = fmaf(tv.z, w, ACC.z);                                   \
      ACC.w = fmaf(tv.w, w, ACC.w); }
      int j = 0;
      for (; j + 4 * NG <= m; j += 4 * NG) {
        CHUNK(j, a0)
        CHUNK(j + NG, a1)
        CHUNK(j + 2 * NG, a2)
        CHUNK(j + 3 * NG, a3)
      }
      for (; j < m; j += NG) CHUNK(j, a0)
#undef CHUNK
    }
    float4 acc;
    acc.x = (a0.x + a1.x) + (a2.x + a3.x);
    acc.y = (a0.y + a1.y) + (a2.y + a3.y);
    acc.z = (a0.z + a1.z) + (a2.z + a3.z);
    acc.w = (a0.w + a1.w) + (a2.w + a3.w);
    if (NG == 4) {  // LPG=16: butterfly across the 4 groups
      acc.x += __shfl_xor(acc.x, 16); acc.y += __shfl_xor(acc.y, 16);
      acc.z += __shfl_xor(acc.z, 16); acc.w += __shfl_xor(acc.w, 16);
      acc.x += __shfl_xor(acc.x, 32); acc.y += __shfl_xor(acc.y, 32);
      acc.z += __shfl_xor(acc.z, 32); acc.w += __shfl_xor(acc.w, 32);
    } else {        // gather-reduce to lanes 0..LPG-1
      float4 tot = acc;
#pragma unroll
      for (int gg = 1; gg < NG; ++gg) {
        tot.x += __shfl(acc.x, c4 + gg * LPG);
        tot.y += __shfl(acc.y, c4 + gg * LPG);
        tot.z += __shfl(acc.z, c4 + gg * LPG);
        tot.w += __shfl(acc.w, c4 + gg * LPG);
      }
      acc = tot;
    }
    if (lane < LPG) {
      const float dn = dis[node], sn = selfn[node];
      const float4 sv = *(const float4*)(t + (size_t)node * C + lane * 4);
      v.x = fmaf(dn, acc.x, sv.x * sn);
      v.y = fmaf(dn, acc.y, sv.y * sn);
      v.z = fmaf(dn, acc.z, sv.z * sn);
      v.w = fmaf(dn, acc.w, sv.w * sn);
      *(float4*)(out + (size_t)node * C + lane * 4) = v;
    }
  }
  if (STATS) {
    if (lane < LPG) {
      atomicAdd(&s_sum[lane * 4 + 0], v.x);
      atomicAdd(&s_sum[lane * 4 + 1], v.y);
      atomicAdd(&s_sum[lane * 4 + 2], v.z);
      atomicAdd(&s_sum[lane * 4 + 3], v.w);
      atomicAdd(&s_sq[lane * 4 + 0], v.x * v.x);
      atomicAdd(&s_sq[lane * 4 + 1], v.y * v.y);
      atomicAdd(&s_sq[lane * 4 + 2], v.z * v.z);
      atomicAdd(&s_sq[lane * 4 + 3], v.w * v.w);
    }
    __syncthreads();
    if (threadIdx.x < 128) {
      const int c = threadIdx.x & 63;
      const float val = (threadIdx.x < 64) ? s_sum[c] : s_sq[c];
      atomicAdd(&part[(blockIdx.x & 63) * 128 + (threadIdx.x < 64 ? c : 64 + c)], val);
    }
  }
}

__global__ void bnfinal_k(const float* __restrict__ part, const float* __restrict__ g,
                          const float* __restrict__ be, float* __restrict__ scale,
                          float* __restrict__ shift) {
  const int c = threadIdx.x;  // 64 threads
  float s = 0.f, q = 0.f;
  for (int b = 0; b < 64; ++b) { s += part[b * 128 + c]; q += part[b * 128 + 64 + c]; }
  const float inv = 1.0f / (float)N_NODES;
  const float mu = s * inv;
  const float var = q * inv - mu * mu;
  const float sc = g[c] * rsqrtf(var + 1e-5f);
  scale[c] = sc;
  shift[c] = fmaf(-mu, sc, be[c]);
}

// ---------------- launch ----------------

extern "C" void kernel_launch(void* const* d_in, const int* in_sizes, int n_in,
                              void* d_out, int out_size, void* d_ws, size_t ws_size,
                              hipStream_t stream) {
  const float* x   = (const float*)d_in[0];
  const int*   ei  = (const int*)d_in[1];
  const float* W1  = (const float*)d_in[2];
  const float* b1  = (const float*)d_in[3];
  const float* g1  = (const float*)d_in[4];
  const float* be1 = (const float*)d_in[5];
  const float* W2  = (const float*)d_in[6];
  const float* b2  = (const float*)d_in[7];
  const float* g2  = (const float*)d_in[8];
  const float* be2 = (const float*)d_in[9];
  const float* W3  = (const float*)d_in[10];
  const float* b3  = (const float*)d_in[11];
  float* out = (float*)d_out;
  const int* src = ei;
  const int* dst = ei + N_EDGES;

  char* ws = (char*)d_ws;
  size_t o = 0;
  auto alloc = [&](size_t bytes) -> char* {
    char* p = ws + o;
    o += (bytes + 255) & ~(size_t)255;
    return p;
  };
  int*   gCount  = (int*)alloc((size_t)NBKT * 4);
  int*   gBase   = (int*)alloc(((size_t)NBKT + 1) * 4);
  int*   gCursor = (int*)alloc((size_t)NBKT * 4);
  int*   offsets = (int*)alloc(((size_t)N_NODES + 1) * 4);
  int*   csr_src = (int*)alloc((size_t)N_EDGES * 4);
  float* dis     = (float*)alloc((size_t)N_NODES * 4);
  float* selfn   = (float*)alloc((size_t)N_NODES * 4);
  float* part1   = (float*)alloc(64 * 128 * 4);  // 32 KiB
  float* part2   = (float*)alloc(64 * 128 * 4);  // contiguous with part1
  float* scale1  = (float*)alloc(64 * 4);
  float* shift1  = (float*)alloc(64 * 4);
  float* scale2  = (float*)alloc(64 * 4);
  float* shift2  = (float*)alloc(64 * 4);
  float* tbuf    = (float*)alloc((size_t)N_NODES * 64 * 4);
  float* hbuf    = (float*)alloc((size_t)N_NODES * 64 * 4);
  // ebuf (12.8 MB) aliases tbuf (25.6 MB): CSR build completes before gemm1
  // writes tbuf; same-stream ordering makes this safe.
  uint2* ebuf = (uint2*)tbuf;

  hipMemsetAsync(gCount, 0, (size_t)NBKT * 4, stream);
  hipMemsetAsync(part1, 0, 2 * 64 * 128 * 4, stream);  // part1+part2

  bucket_count_k<<<NBLK_E, 256, 0, stream>>>(dst, gCount);
  bucket_scan_k<<<1, 256, 0, stream>>>(gCount, gBase, gCursor, offsets);
  bucket_scatter_k<<<NBLK_E, 256, 0, stream>>>(src, dst, gCursor, ebuf);
  csr_build_k<<<NBKT, 256, 0, stream>>>(ebuf, gBase, offsets, csr_src, dis, selfn);

  // layer 1: K=128 -> C=64, no BN on input
  gemm_k<128, 64, 2, false><<<(N_NODES + 31) / 32, 256, 0, stream>>>(
      x, W1, b1, nullptr, nullptr, tbuf);
  agg_k<64, 4, 16, true><<<(N_NODES + 3) / 4, 256, 0, stream>>>(
      tbuf, csr_src, offsets, dis, selfn, hbuf, part1);
  bnfinal_k<<<1, 64, 0, stream>>>(part1, g1, be1, scale1, shift1);

  // layer 2: K=64 -> C=64, BN+ReLU fused into A staging
  gemm_k<64, 64, 4, true><<<(N_NODES + 63) / 64, 256, 0, stream>>>(
      hbuf, W2, b2, scale1, shift1, tbuf);
  agg_k<64, 4, 16, true><<<(N_NODES + 3) / 4, 256, 0, stream>>>(
      tbuf, csr_src, offsets, dis, selfn, hbuf, part2);
  bnfinal_k<<<1, 64, 0, stream>>>(part2, g2, be2, scale2, shift2);

  // layer 3: K=64 -> C=40, BN+ReLU fused; aggregate straight to d_out
  gemm_k<64, 40, 4, true><<<(N_NODES + 99) / 100, 256, 0, stream>>>(
      hbuf, W3, b3, scale2, shift2, tbuf);
  agg_k<40, 6, 10, false><<<(N_NODES + 3) / 4, 256, 0, stream>>>(
      tbuf, csr_src, offsets, dis, selfn, out, nullptr);
}

// Round 5
// 533.727 us; speedup vs baseline: 1.5446x; 1.0156x over previous
//
#include <hip/hip_runtime.h>

#define N_NODES 100000
#define N_EDGES 1600000
#define NBKT 391            // bucket = dst >> 8, 256 nodes per bucket
#define EPB 4096            // edges per block in bucket passes
#define NBLK_E ((N_EDGES + EPB - 1) / EPB)  // 391

typedef unsigned short u16;
typedef unsigned int u32;
struct alignas(8) bf4 { u16 a, b, c, d; };

__device__ __forceinline__ float blo(u32 u) { return __uint_as_float(u << 16); }
__device__ __forceinline__ float bhi(u32 u) { return __uint_as_float(u & 0xffff0000u); }
__device__ __forceinline__ u16 f2bf(float f) {  // RTNE
  u32 u = __float_as_uint(f);
  return (u16)((u + 0x7fffu + ((u >> 16) & 1u)) >> 16);
}

// ---------------- CSR build: two-level bucket counting sort ----------------

__global__ __launch_bounds__(256) void bucket_count_k(const int* __restrict__ dst,
                                                      int* __restrict__ gCount) {
  __shared__ int h[NBKT];
  for (int i = threadIdx.x; i < NBKT; i += 256) h[i] = 0;
  __syncthreads();
  const int e0 = blockIdx.x * EPB;
  const int eN = min(EPB, N_EDGES - e0);
  for (int i = threadIdx.x; i < eN; i += 256) atomicAdd(&h[dst[e0 + i] >> 8], 1);
  __syncthreads();
  for (int i = threadIdx.x; i < NBKT; i += 256)
    if (h[i]) atomicAdd(&gCount[i], h[i]);
}

__global__ void bucket_scan_k(const int* __restrict__ gCount,
                              int* __restrict__ gBase,
                              int* __restrict__ gCursor,
                              int* __restrict__ offsets) {
  __shared__ int sm[512];
  const int t = threadIdx.x;  // 256
  const int c0 = (t < NBKT) ? gCount[t] : 0;
  const int c1 = (t + 256 < NBKT) ? gCount[t + 256] : 0;
  sm[t] = c0; sm[t + 256] = c1;
  __syncthreads();
  for (int off = 1; off < 512; off <<= 1) {
    const int v0 = (t >= off) ? sm[t - off] : 0;
    const int v1 = (t + 256 >= off) ? sm[t + 256 - off] : 0;
    __syncthreads();
    sm[t] += v0; sm[t + 256] += v1;
    __syncthreads();
  }
  if (t < NBKT)       { const int b = sm[t] - c0;       gBase[t] = b;       gCursor[t] = b; }
  if (t + 256 < NBKT) { const int b = sm[t + 256] - c1; gBase[t + 256] = b; gCursor[t + 256] = b; }
  if (t == 0) { gBase[NBKT] = N_EDGES; offsets[N_NODES] = N_EDGES; }
}

// chunk -> LDS counting-sort by bucket -> coalesced run writes into ebuf
__global__ __launch_bounds__(256) void bucket_scatter_k(const int* __restrict__ src,
                                                        const int* __restrict__ dst,
                                                        int* __restrict__ gCursor,
                                                        uint2* __restrict__ ebuf) {
  __shared__ int cnt[NBKT];
  __shared__ int inc[512];
  __shared__ int gb[NBKT];
  __shared__ int cur[NBKT];
  __shared__ uint2 st[EPB];
  const int t = threadIdx.x;
  for (int i = t; i < NBKT; i += 256) cnt[i] = 0;
  __syncthreads();
  const int e0 = blockIdx.x * EPB;
  const int eN = min(EPB, N_EDGES - e0);
  for (int i = t; i < eN; i += 256) atomicAdd(&cnt[dst[e0 + i] >> 8], 1);
  __syncthreads();
  const int c0 = (t < NBKT) ? cnt[t] : 0;
  const int c1 = (t + 256 < NBKT) ? cnt[t + 256] : 0;
  inc[t] = c0; inc[t + 256] = c1;
  __syncthreads();
  for (int off = 1; off < 512; off <<= 1) {
    const int v0 = (t >= off) ? inc[t - off] : 0;
    const int v1 = (t + 256 >= off) ? inc[t + 256 - off] : 0;
    __syncthreads();
    inc[t] += v0; inc[t + 256] += v1;
    __syncthreads();
  }
  if (t < NBKT) {
    if (c0) gb[t] = atomicAdd(&gCursor[t], c0);
    cur[t] = inc[t] - c0;
  }
  if (t + 256 < NBKT) {
    if (c1) gb[t + 256] = atomicAdd(&gCursor[t + 256], c1);
    cur[t + 256] = inc[t + 256] - c1;
  }
  __syncthreads();
  for (int i = t; i < eN; i += 256) {
    const int d = dst[e0 + i];
    const int b = d >> 8;
    const int p = atomicAdd(&cur[b], 1);
    st[p] = make_uint2((unsigned)src[e0 + i], (unsigned)d);
  }
  __syncthreads();
  for (int i = t; i < eN; i += 256) {
    const uint2 e = st[i];
    const int b = (int)(e.y >> 8);
    const int excl = inc[b] - cnt[b];
    ebuf[gb[b] + (i - excl)] = e;   // adjacent i in a run -> adjacent addrs
  }
}

// one block per bucket: per-node count/scan/scatter in LDS; emits offsets,
// degree-derived dis/selfn, and csr_src (stores confined to one CU's region)
__global__ __launch_bounds__(256) void csr_build_k(const uint2* __restrict__ ebuf,
                                                   const int* __restrict__ gBase,
                                                   int* __restrict__ offsets,
                                                   int* __restrict__ csr_src,
                                                   float* __restrict__ dis,
                                                   float* __restrict__ selfn) {
  __shared__ int cnt[256];
  __shared__ int inc[256];
  __shared__ int cur[256];
  const int t = threadIdx.x;
  const int b = blockIdx.x;
  const int ebeg = gBase[b], eend = gBase[b + 1];
  cnt[t] = 0;
  __syncthreads();
  for (int e = ebeg + t; e < eend; e += 256) atomicAdd(&cnt[ebuf[e].y & 255], 1);
  __syncthreads();
  const int c = cnt[t];
  inc[t] = c;
  __syncthreads();
  for (int off = 1; off < 256; off <<= 1) {
    const int v = (t >= off) ? inc[t - off] : 0;
    __syncthreads();
    inc[t] += v;
    __syncthreads();
  }
  const int node = (b << 8) + t;
  const int goff = ebeg + inc[t] - c;
  cur[t] = goff;
  if (node < N_NODES) {
    offsets[node] = goff;
    const float deg = (float)c + 1.0f;  // +1 self loop
    dis[node] = rsqrtf(deg);
    selfn[node] = 1.0f / deg;
  }
  __syncthreads();
  for (int e = ebeg + t; e < eend; e += 256) {
    const uint2 ed = ebuf[e];
    const int p = atomicAdd(&cur[ed.y & 255], 1);
    csr_src[p] = (int)ed.x;
  }
}

// ---------------- GEMM: out[N,C] = act(A)[N,K] @ W[K,C] + bias, bf16 out ------
// act = identity (BN=false) or relu(a*scale[k]+shift[k]) (BN=true), fused at staging.

template <int K, int C, int RPT, bool BN>
__global__ __launch_bounds__(256) void gemm_k(const float* __restrict__ A,
                                              const float* __restrict__ W,
                                              const float* __restrict__ bias,
                                              const float* __restrict__ scale,
                                              const float* __restrict__ shift,
                                              u16* __restrict__ out) {
  constexpr int CQ = C / 4;        // float4 channel groups
  constexpr int TR = 256 / CQ;     // thread row-slots (floor)
  constexpr int ROWS = TR * RPT;   // rows per block
  __shared__ __align__(16) float Wl[K * C];
  __shared__ __align__(16) float Al[ROWS * K];
  const int tid = threadIdx.x;
  for (int i = tid; i < K * C; i += 256) Wl[i] = W[i];
  const int row0 = blockIdx.x * ROWS;
  for (int i = tid; i < ROWS * K; i += 256) {
    int r = i / K, k = i - r * K;
    int gr = row0 + r;
    float v = 0.f;
    if (gr < N_NODES) {
      v = A[(size_t)gr * K + k];
      if (BN) v = fmaxf(fmaf(v, scale[k], shift[k]), 0.f);
    }
    Al[i] = v;
  }
  __syncthreads();
  const int cq = tid % CQ;
  const int rs = tid / CQ;
  if (rs >= TR) return;  // only possible when 256 % CQ != 0 (C=40); no further barriers
  const float4* W4 = (const float4*)Wl;
  const float4* A4 = (const float4*)Al;
  float4 acc[RPT];
#pragma unroll
  for (int i = 0; i < RPT; ++i) acc[i] = make_float4(0.f, 0.f, 0.f, 0.f);
#pragma unroll 4
  for (int k4 = 0; k4 < K / 4; ++k4) {
    float4 w0 = W4[(4 * k4 + 0) * CQ + cq];
    float4 w1 = W4[(4 * k4 + 1) * CQ + cq];
    float4 w2 = W4[(4 * k4 + 2) * CQ + cq];
    float4 w3 = W4[(4 * k4 + 3) * CQ + cq];
#pragma unroll
    for (int i = 0; i < RPT; ++i) {
      float4 a = A4[(rs * RPT + i) * (K / 4) + k4];
      acc[i].x = fmaf(a.x, w0.x, acc[i].x); acc[i].y = fmaf(a.x, w0.y, acc[i].y);
      acc[i].z = fmaf(a.x, w0.z, acc[i].z); acc[i].w = fmaf(a.x, w0.w, acc[i].w);
      acc[i].x = fmaf(a.y, w1.x, acc[i].x); acc[i].y = fmaf(a.y, w1.y, acc[i].y);
      acc[i].z = fmaf(a.y, w1.z, acc[i].z); acc[i].w = fmaf(a.y, w1.w, acc[i].w);
      acc[i].x = fmaf(a.z, w2.x, acc[i].x); acc[i].y = fmaf(a.z, w2.y, acc[i].y);
      acc[i].z = fmaf(a.z, w2.z, acc[i].z); acc[i].w = fmaf(a.z, w2.w, acc[i].w);
      acc[i].x = fmaf(a.w, w3.x, acc[i].x); acc[i].y = fmaf(a.w, w3.y, acc[i].y);
      acc[i].z = fmaf(a.w, w3.z, acc[i].z); acc[i].w = fmaf(a.w, w3.w, acc[i].w);
    }
  }
  float4 b4 = ((const float4*)bias)[cq];
#pragma unroll
  for (int i = 0; i < RPT; ++i) {
    int gr = row0 + rs * RPT + i;
    if (gr < N_NODES) {
      bf4 o;
      o.a = f2bf(acc[i].x + b4.x); o.b = f2bf(acc[i].y + b4.y);
      o.c = f2bf(acc[i].z + b4.z); o.d = f2bf(acc[i].w + b4.w);
      *(bf4*)(out + (size_t)gr * C + cq * 4) = o;
    }
  }
}

// ---------------- aggregation (bf16 table) ----------------
// out[n] = dis[n]*sum_{e:dst=n} t[src_e]*dis[src_e] + t[n]*selfn[n]
// C=64: wave = 8 groups x 8 lanes; lane loads uint4 = 8 bf16 -> one
// global_load_dwordx4 gathers 8 edge rows (1 KB). 2-deep unroll = 16 edges
// in flight (~avg degree). fp32 accumulate; optional fused BN stats.

template <bool STATS>
__global__ __launch_bounds__(256) void agg64_k(const u16* __restrict__ tb,
                                               const int* __restrict__ csr,
                                               const int* __restrict__ offs,
                                               const float* __restrict__ dis,
                                               const float* __restrict__ selfn,
                                               float* __restrict__ out,
                                               float* __restrict__ part) {
  __shared__ float s_sum[64];
  __shared__ float s_sq[64];
  if (STATS) {
    if (threadIdx.x < 64) { s_sum[threadIdx.x] = 0.f; s_sq[threadIdx.x] = 0.f; }
    __syncthreads();
  }
  const int lane = threadIdx.x & 63;
  const int node = blockIdx.x * 4 + (threadIdx.x >> 6);
  const int g = lane >> 3;       // edge group 0..7
  const int c4 = lane & 7;       // 8-channel slot within row
  float v[8];
#pragma unroll
  for (int k = 0; k < 8; ++k) v[k] = 0.f;
  if (node < N_NODES) {
    const int beg = offs[node], end = offs[node + 1];
    float a0[8], a1[8];
#pragma unroll
    for (int k = 0; k < 8; ++k) { a0[k] = 0.f; a1[k] = 0.f; }
    const u16* __restrict__ tc = tb + (c4 << 3);
    for (int base = beg; base < end; base += 64) {
      const int m = min(64, end - base);
      int sl = 0; float wl = 0.f;
      if (lane < m) { sl = csr[base + lane]; wl = dis[sl]; }
#define CHUNK64(JJ, ACC) {                                            \
      const int idx = (JJ) + g;                                       \
      int s = __shfl(sl, idx);                                        \
      float w = __shfl(wl, idx);                                      \
      if (idx >= m) { s = 0; w = 0.f; }                               \
      const uint4 q = *(const uint4*)(tc + (size_t)s * 64);           \
      ACC[0] = fmaf(blo(q.x), w, ACC[0]);                             \
      ACC[1] = fmaf(bhi(q.x), w, ACC[1]);                             \
      ACC[2] = fmaf(blo(q.y), w, ACC[2]);                             \
      ACC[3] = fmaf(bhi(q.y), w, ACC[3]);                             \
      ACC[4] = fmaf(blo(q.z), w, ACC[4]);                             \
      ACC[5] = fmaf(bhi(q.z), w, ACC[5]);                             \
      ACC[6] = fmaf(blo(q.w), w, ACC[6]);                             \
      ACC[7] = fmaf(bhi(q.w), w, ACC[7]); }
      int j = 0;
      for (; j + 16 <= m; j += 16) {
        CHUNK64(j, a0)
        CHUNK64(j + 8, a1)
      }
      for (; j < m; j += 8) CHUNK64(j, a0)
#undef CHUNK64
    }
    float acc[8];
#pragma unroll
    for (int k = 0; k < 8; ++k) acc[k] = a0[k] + a1[k];
    // butterfly sum across the 8 groups (keep c4 position)
#pragma unroll
    for (int k = 0; k < 8; ++k) {
      acc[k] += __shfl_xor(acc[k], 8);
      acc[k] += __shfl_xor(acc[k], 16);
      acc[k] += __shfl_xor(acc[k], 32);
    }
    if (lane < 8) {
      const float dn = dis[node], sn = selfn[node];
      const uint4 q = *(const uint4*)(tb + (size_t)node * 64 + (c4 << 3));
      const float sv[8] = {blo(q.x), bhi(q.x), blo(q.y), bhi(q.y),
                           blo(q.z), bhi(q.z), blo(q.w), bhi(q.w)};
#pragma unroll
      for (int k = 0; k < 8; ++k) v[k] = fmaf(dn, acc[k], sv[k] * sn);
      float4* op = (float4*)(out + (size_t)node * 64 + (c4 << 3));
      op[0] = make_float4(v[0], v[1], v[2], v[3]);
      op[1] = make_float4(v[4], v[5], v[6], v[7]);
    }
  }
  if (STATS) {
    if ((threadIdx.x & 63) < 8) {
      const int c0 = (threadIdx.x & 7) << 3;
#pragma unroll
      for (int k = 0; k < 8; ++k) {
        atomicAdd(&s_sum[c0 + k], v[k]);
        atomicAdd(&s_sq[c0 + k], v[k] * v[k]);
      }
    }
    __syncthreads();
    if (threadIdx.x < 128) {
      const int c = threadIdx.x & 63;
      const float val = (threadIdx.x < 64) ? s_sum[c] : s_sq[c];
      atomicAdd(&part[(blockIdx.x & 63) * 128 + (threadIdx.x < 64 ? c : 64 + c)], val);
    }
  }
}

// C=40: wave = 6 groups x 10 lanes; lane loads uint2 = 4 bf16 (8 B).
__global__ __launch_bounds__(256) void agg40_k(const u16* __restrict__ tb,
                                               const int* __restrict__ csr,
                                               const int* __restrict__ offs,
                                               const float* __restrict__ dis,
                                               const float* __restrict__ selfn,
                                               float* __restrict__ out) {
  const int lane = threadIdx.x & 63;
  const int node = blockIdx.x * 4 + (threadIdx.x >> 6);
  const int g = lane / 10;        // 0..6 (g==6 inactive)
  const int c4 = lane - g * 10;   // 4-channel slot 0..9
  const bool active = (lane < 60);
  if (node >= N_NODES) return;
  const int beg = offs[node], end = offs[node + 1];
  float a0[4], a1[4];
#pragma unroll
  for (int k = 0; k < 4; ++k) { a0[k] = 0.f; a1[k] = 0.f; }
  const u16* __restrict__ tc = tb + (c4 << 2);
  for (int base = beg; base < end; base += 64) {
    const int m = min(64, end - base);
    int sl = 0; float wl = 0.f;
    if (lane < m) { sl = csr[base + lane]; wl = dis[sl]; }
#define CHUNK40(JJ, ACC) {                                            \
    const int idx = (JJ) + g;                                         \
    int s = __shfl(sl, idx);                                          \
    float w = __shfl(wl, idx);                                        \
    if (!active || idx >= m) { s = 0; w = 0.f; }                      \
    const uint2 q = *(const uint2*)(tc + (size_t)s * 40);             \
    ACC[0] = fmaf(blo(q.x), w, ACC[0]);                               \
    ACC[1] = fmaf(bhi(q.x), w, ACC[1]);                               \
    ACC[2] = fmaf(blo(q.y), w, ACC[2]);                               \
    ACC[3] = fmaf(bhi(q.y), w, ACC[3]); }
    int j = 0;
    for (; j + 12 <= m; j += 12) {
      CHUNK40(j, a0)
      CHUNK40(j + 6, a1)
    }
    for (; j < m; j += 6) CHUNK40(j, a0)
#undef CHUNK40
  }
  float acc[4];
#pragma unroll
  for (int k = 0; k < 4; ++k) acc[k] = a0[k] + a1[k];
  float tot[4] = {acc[0], acc[1], acc[2], acc[3]};
#pragma unroll
  for (int gg = 1; gg < 6; ++gg) {
#pragma unroll
    for (int k = 0; k < 4; ++k) tot[k] += __shfl(acc[k], c4 + gg * 10);
  }
  if (lane < 10) {
    const float dn = dis[node], sn = selfn[node];
    const uint2 q = *(const uint2*)(tb + (size_t)node * 40 + (c4 << 2));
    const float sv[4] = {blo(q.x), bhi(q.x), blo(q.y), bhi(q.y)};
    float4 o;
    o.x = fmaf(dn, tot[0], sv[0] * sn);
    o.y = fmaf(dn, tot[1], sv[1] * sn);
    o.z = fmaf(dn, tot[2], sv[2] * sn);
    o.w = fmaf(dn, tot[3], sv[3] * sn);
    *(float4*)(out + (size_t)node * 40 + (c4 << 2)) = o;
  }
}

__global__ void bnfinal_k(const float* __restrict__ part, const float* __restrict__ g,
                          const float* __restrict__ be, float* __restrict__ scale,
                          float* __restrict__ shift) {
  const int c = threadIdx.x;  // 64 threads
  float s = 0.f, q = 0.f;
  for (int b = 0; b < 64; ++b) { s += part[b * 128 + c]; q += part[b * 128 + 64 + c]; }
  const float inv = 1.0f / (float)N_NODES;
  const float mu = s * inv;
  const float var = q * inv - mu * mu;
  const float sc = g[c] * rsqrtf(var + 1e-5f);
  scale[c] = sc;
  shift[c] = fmaf(-mu, sc, be[c]);
}

// ---------------- launch ----------------

extern "C" void kernel_launch(void* const* d_in, const int* in_sizes, int n_in,
                              void* d_out, int out_size, void* d_ws, size_t ws_size,
                              hipStream_t stream) {
  const float* x   = (const float*)d_in[0];
  const int*   ei  = (const int*)d_in[1];
  const float* W1  = (const float*)d_in[2];
  const float* b1  = (const float*)d_in[3];
  const float* g1  = (const float*)d_in[4];
  const float* be1 = (const float*)d_in[5];
  const float* W2  = (const float*)d_in[6];
  const float* b2  = (const float*)d_in[7];
  const float* g2  = (const float*)d_in[8];
  const float* be2 = (const float*)d_in[9];
  const float* W3  = (const float*)d_in[10];
  const float* b3  = (const float*)d_in[11];
  float* out = (float*)d_out;
  const int* src = ei;
  const int* dst = ei + N_EDGES;

  char* ws = (char*)d_ws;
  size_t o = 0;
  auto alloc = [&](size_t bytes) -> char* {
    char* p = ws + o;
    o += (bytes + 255) & ~(size_t)255;
    return p;
  };
  int*   gCount  = (int*)alloc((size_t)NBKT * 4);
  int*   gBase   = (int*)alloc(((size_t)NBKT + 1) * 4);
  int*   gCursor = (int*)alloc((size_t)NBKT * 4);
  int*   offsets = (int*)alloc(((size_t)N_NODES + 1) * 4);
  int*   csr_src = (int*)alloc((size_t)N_EDGES * 4);
  float* dis     = (float*)alloc((size_t)N_NODES * 4);
  float* selfn   = (float*)alloc((size_t)N_NODES * 4);
  float* part1   = (float*)alloc(64 * 128 * 4);  // 32 KiB
  float* part2   = (float*)alloc(64 * 128 * 4);  // contiguous with part1
  float* scale1  = (float*)alloc(64 * 4);
  float* shift1  = (float*)alloc(64 * 4);
  float* scale2  = (float*)alloc(64 * 4);
  float* shift2  = (float*)alloc(64 * 4);
  u16*   tbuf    = (u16*)alloc((size_t)N_NODES * 64 * 4);  // bf16 table (also hosts ebuf)
  float* hbuf    = (float*)alloc((size_t)N_NODES * 64 * 4);
  // ebuf (12.8 MB) aliases tbuf region: CSR build completes before gemm1
  // writes tbuf; same-stream ordering makes this safe.
  uint2* ebuf = (uint2*)tbuf;

  hipMemsetAsync(gCount, 0, (size_t)NBKT * 4, stream);
  hipMemsetAsync(part1, 0, 2 * 64 * 128 * 4, stream);  // part1+part2

  bucket_count_k<<<NBLK_E, 256, 0, stream>>>(dst, gCount);
  bucket_scan_k<<<1, 256, 0, stream>>>(gCount, gBase, gCursor, offsets);
  bucket_scatter_k<<<NBLK_E, 256, 0, stream>>>(src, dst, gCursor, ebuf);
  csr_build_k<<<NBKT, 256, 0, stream>>>(ebuf, gBase, offsets, csr_src, dis, selfn);

  // layer 1: K=128 -> C=64, no BN on input
  gemm_k<128, 64, 2, false><<<(N_NODES + 31) / 32, 256, 0, stream>>>(
      x, W1, b1, nullptr, nullptr, tbuf);
  agg64_k<true><<<(N_NODES + 3) / 4, 256, 0, stream>>>(
      tbuf, csr_src, offsets, dis, selfn, hbuf, part1);
  bnfinal_k<<<1, 64, 0, stream>>>(part1, g1, be1, scale1, shift1);

  // layer 2: K=64 -> C=64, BN+ReLU fused into A staging
  gemm_k<64, 64, 4, true><<<(N_NODES + 63) / 64, 256, 0, stream>>>(
      hbuf, W2, b2, scale1, shift1, tbuf);
  agg64_k<true><<<(N_NODES + 3) / 4, 256, 0, stream>>>(
      tbuf, csr_src, offsets, dis, selfn, hbuf, part2);
  bnfinal_k<<<1, 64, 0, stream>>>(part2, g2, be2, scale2, shift2);

  // layer 3: K=64 -> C=40, BN+ReLU fused; aggregate straight to d_out
  gemm_k<64, 40, 4, true><<<(N_NODES + 99) / 100, 256, 0, stream>>>(
      hbuf, W3, b3, scale2, shift2, tbuf);
  agg40_k<<<(N_NODES + 3) / 4, 256, 0, stream>>>(
      tbuf, csr_src, offsets, dis, selfn, out);
}